// Round 14
// baseline (38.417 us; speedup 1.0000x reference)
//
#include <hip/hip_runtime.h>

// out[b,o,c,l] = time[b,c,l] * sum_{i,k} W[o,i,c,k] * x[b,i,c,l+k-1]  (x zero-padded in l)
// b=16, i=64, c=4, L=4096, o=64, K=3
//
// r11 chassis (best: 33.05us) + NON-TEMPORAL output stores: out is 65.5MB
// write-once/never-read; nt keeps it from write-allocating in L2/L3, which
// preserves x's L3 residency (FETCH 42MB < 64MB shows x is cache-resident)
// and decongests the TCCs. Single-variable A/B vs r11.
// Chassis: 8x32-l chunks/block, ONE contiguous 258-row LDS tile (halos free),
// stage-ahead-by-2, lgkm-only barriers, prepacked W, float4 epilogue.

#define NB 16
#define NI 64
#define NC 4
#define NL 4096
#define NO 64
#define KW 3
#define LT 32                 // chunk length
#define NCH 8                 // chunks per block
#define LBLK (LT * NCH)       // 256 l per block
#define ROWS (LBLK + 2)       // 258
#define ROWB 128              // 64 i * 2B
#define LDSB (ROWS * ROWB)    // 33024

#define W_PACK_BYTES (NO * NI * NC * KW * 2)   // 98304

typedef float f32x4 __attribute__((ext_vector_type(4)));
typedef short bf16x8 __attribute__((ext_vector_type(8)));

__device__ inline unsigned short f2bf(float f) {
    unsigned int u = __builtin_bit_cast(unsigned int, f);
    u += 0x7FFFu + ((u >> 16) & 1u);          // round-to-nearest-even
    return (unsigned short)(u >> 16);
}

__device__ __forceinline__ void block_sync_lds() {
    asm volatile("s_waitcnt lgkmcnt(0)" ::: "memory");
    __builtin_amdgcn_s_barrier();
    asm volatile("" ::: "memory");
}

// ---- kernel 1: pack W (coalesced read, scattered 2B write) ----
// dest flat bf16 index = (((c*4 + wv)*6 + cc)*64 + lane)*8 + j  where
// o = wv*16 + (lane&15), i = (cc&1)*32 + (lane>>4)*8 + j, k = cc>>1
__global__ __launch_bounds__(256)
void prepack_w_kernel(const float* __restrict__ w, unsigned short* __restrict__ wp) {
    const int idx = blockIdx.x * 256 + threadIdx.x;      // 49152 = o*i*c*k
    const float v = w[idx];                              // coalesced
    const int k = idx % 3;
    int r = idx / 3;
    const int c = r & 3;  r >>= 2;
    const int i = r & 63;
    const int o = r >> 6;
    const int cc   = k * 2 + (i >> 5);
    const int lane = (((i >> 3) & 3) << 4) | (o & 15);
    const int j    = i & 7;
    const int wv   = o >> 4;
    wp[(((c * 4 + wv) * 6 + cc) * 64 + lane) * 8 + j] = f2bf(v);
}

// ---- staging: g2 = t>>3 (2-i group), q = t&7 (l-quad) ----
__device__ __forceinline__ void stage_load(const float* __restrict__ xb,
                                           int l0q, int g2, f32x4 s[2]) {
    const float* p = xb + (size_t)(2 * g2) * (NC * NL) + l0q;
    s[0] = *(const f32x4*)(p);
    s[1] = *(const f32x4*)(p + NC * NL);
}

__device__ __forceinline__ void stage_write(char* __restrict__ lds,
                                            int ch, int q, int g2,
                                            const f32x4 s[2]) {
#pragma unroll
    for (int r = 0; r < 4; ++r) {
        const int row = ch * LT + 4 * q + r + 1;         // rows 1..256
        const unsigned int pk =
            (unsigned int)f2bf(s[0][r]) | ((unsigned int)f2bf(s[1][r]) << 16);
        *(unsigned int*)(lds + row * ROWB + ((4 * g2) ^ ((row & 7) << 4))) = pk;
    }
}

// ---- compute: wave (oh,lh) does 16 l x 32 o; 6 ds_read -> 12 MFMA (1:2) ----
__device__ __forceinline__ void compute_chunk(const char* __restrict__ lds,
                                              const bf16x8 wfrag[2][6],
                                              const float* __restrict__ tb,
                                              float* __restrict__ ob0,
                                              float* __restrict__ ob1,
                                              int ch, int lb0, int lane, int lh) {
    const int lcol  = lane & 15;
    const int ksub2 = (lane >> 4) * 16;
    const int l0 = lb0 + ch * LT + lh * 16 + (lane >> 4) * 4;
    const f32x4 tv = *(const f32x4*)(tb + l0);

    f32x4 acc0 = {}, acc1 = {};
#pragma unroll
    for (int cc = 0; cc < 6; ++cc) {
        const int row = ch * LT + lh * 16 + lcol + (cc >> 1);
        const int off = row * ROWB + ((((cc & 1) << 6) + ksub2) ^ ((row & 7) << 4));
        const bf16x8 xf = *(const bf16x8*)(lds + off);
        acc0 = __builtin_amdgcn_mfma_f32_16x16x32_bf16(xf, wfrag[0][cc], acc0, 0, 0, 0);
        acc1 = __builtin_amdgcn_mfma_f32_16x16x32_bf16(xf, wfrag[1][cc], acc1, 0, 0, 0);
    }
    f32x4 r0, r1;
#pragma unroll
    for (int qq = 0; qq < 4; ++qq) { r0[qq] = acc0[qq] * tv[qq]; r1[qq] = acc1[qq] * tv[qq]; }
    __builtin_nontemporal_store(r0, (f32x4*)(ob0 + l0));   // nt: no write-allocate
    __builtin_nontemporal_store(r1, (f32x4*)(ob1 + l0));
}

__global__ __launch_bounds__(256, 4)
void tconv_mfma_kernel(const float* __restrict__ x,
                       const float* __restrict__ tt,
                       const unsigned short* __restrict__ wp,
                       float* __restrict__ out)
{
    __shared__ char lds[LDSB];                           // 33 024 B

    const int t    = threadIdx.x;
    const int lane = t & 63;
    const int wave = t >> 6;
    const int oh   = wave >> 1;                          // o half (32 o)
    const int lh   = wave & 1;                           // l half of chunk (16 l)
    const int c    = blockIdx.y;
    const int b    = blockIdx.z;
    const int lb0  = blockIdx.x * LBLK;
    const int g2   = t >> 3;                             // 0..31
    const int q    = t & 7;                              // 0..7
    const int lq   = 4 * q;

    const float* xb = x + ((size_t)b * NI * NC + c) * NL;
    const float* tb = tt + (size_t)(b * NC + c) * NL;
    float* ob0 = out + ((size_t)b * NO * NC
                        + (size_t)(oh * 32 + (lane & 15)) * NC + c) * NL;
    float* ob1 = ob0 + (size_t)16 * NC * NL;

    // ---- prologue: chunks 0,1 + halo loads first (HBM critical path)
    f32x4 sA[2], sB[2];
    stage_load(xb, lb0 + 0 * LT + lq, g2, sA);
    stage_load(xb, lb0 + 1 * LT + lq, g2, sB);
    float h = 0.f; int hrow = 0, hcol = 0;
    if (t < 128) {                                       // halo rows 0 and 257
        const int which = t & 1;
        const int i     = t >> 1;
        hrow = which ? (LBLK + 1) : 0;
        hcol = 2 * i;
        const int lhh = which ? (lb0 + LBLK) : (lb0 - 1);
        if (lhh >= 0 && lhh < NL) h = xb[(size_t)i * (NC * NL) + lhh];
    }

    // W fragments: o-strips 2oh, 2oh+1 -> 12 coalesced b128, L2-hot
    bf16x8 wfrag[2][6];
    {
        const bf16x8* wpb = (const bf16x8*)wp + (size_t)((c * 4 + oh * 2) * 6) * 64 + lane;
#pragma unroll
        for (int s = 0; s < 2; ++s)
#pragma unroll
            for (int cc = 0; cc < 6; ++cc)
                wfrag[s][cc] = wpb[(s * 6 + cc) * 64];
    }

    stage_write(lds, 0, q, g2, sA);
    stage_write(lds, 1, q, g2, sB);
    if (t < 128)
        *(unsigned short*)(lds + hrow * ROWB + (hcol ^ ((hrow & 7) << 4))) = f2bf(h);
    block_sync_lds();

    // ---- steady state: 6 of 8 iterations overlap load || compute+store || write
#pragma unroll
    for (int cn = 0; cn < NCH - 2; ++cn) {
        if ((cn & 1) == 0) {
            stage_load(xb, lb0 + (cn + 2) * LT + lq, g2, sA);
            compute_chunk(lds, wfrag, tb, ob0, ob1, cn, lb0, lane, lh);
            stage_write(lds, cn + 2, q, g2, sA);
        } else {
            stage_load(xb, lb0 + (cn + 2) * LT + lq, g2, sB);
            compute_chunk(lds, wfrag, tb, ob0, ob1, cn, lb0, lane, lh);
            stage_write(lds, cn + 2, q, g2, sB);
        }
        block_sync_lds();
    }

    // ---- drain
    compute_chunk(lds, wfrag, tb, ob0, ob1, NCH - 2, lb0, lane, lh);
    compute_chunk(lds, wfrag, tb, ob0, ob1, NCH - 1, lb0, lane, lh);
}

extern "C" void kernel_launch(void* const* d_in, const int* in_sizes, int n_in,
                              void* d_out, int out_size, void* d_ws, size_t ws_size,
                              hipStream_t stream) {
    const float* x  = (const float*)d_in[0];
    const float* tt = (const float*)d_in[1];
    const float* w  = (const float*)d_in[2];
    float* out = (float*)d_out;
    unsigned short* wpck = (unsigned short*)d_ws;

    prepack_w_kernel<<<dim3(NO * NI * NC * KW / 256), dim3(256), 0, stream>>>(w, wpck);

    dim3 grid(NL / LBLK, NC, NB);   // (16, 4, 16) = 1024 blocks
    tconv_mfma_kernel<<<grid, dim3(256), 0, stream>>>(x, tt, wpck, out);
}

// Round 15
// 32.622 us; speedup vs baseline: 1.1776x; 1.1776x over previous
//
#include <hip/hip_runtime.h>

// out[b,o,c,l] = time[b,c,l] * sum_{i,k} W[o,i,c,k] * x[b,i,c,l+k-1]  (x zero-padded in l)
// b=16, i=64, c=4, L=4096, o=64, K=3
//
// EXACT REVERT to round-11 (best measured: 33.05us). r14's nt-store A/B
// regressed (64B store islands need L2 write-combining; nt bypasses it).
// Chassis: block = (b,c,256 l) as 8 chunks of 32 l in ONE contiguous 258-row
// LDS tile ([row=l][col=i] bf16, XOR-swizzled; halos free), stage-ahead-by-2
// pipeline (6 of 8 iterations overlap load || compute+store || write),
// lgkm-only barriers (stores/prefetch never drained), W prepacked to
// per-lane fragment order, float4 epilogue with cached stores.

#define NB 16
#define NI 64
#define NC 4
#define NL 4096
#define NO 64
#define KW 3
#define LT 32                 // chunk length
#define NCH 8                 // chunks per block
#define LBLK (LT * NCH)       // 256 l per block
#define ROWS (LBLK + 2)       // 258
#define ROWB 128              // 64 i * 2B
#define LDSB (ROWS * ROWB)    // 33024

#define W_PACK_BYTES (NO * NI * NC * KW * 2)   // 98304

typedef float f32x4 __attribute__((ext_vector_type(4)));
typedef short bf16x8 __attribute__((ext_vector_type(8)));

__device__ inline unsigned short f2bf(float f) {
    unsigned int u = __builtin_bit_cast(unsigned int, f);
    u += 0x7FFFu + ((u >> 16) & 1u);          // round-to-nearest-even
    return (unsigned short)(u >> 16);
}

__device__ __forceinline__ void block_sync_lds() {
    asm volatile("s_waitcnt lgkmcnt(0)" ::: "memory");
    __builtin_amdgcn_s_barrier();
    asm volatile("" ::: "memory");
}

// ---- kernel 1: pack W (coalesced read, scattered 2B write) ----
// dest flat bf16 index = (((c*4 + wv)*6 + cc)*64 + lane)*8 + j  where
// o = wv*16 + (lane&15), i = (cc&1)*32 + (lane>>4)*8 + j, k = cc>>1
__global__ __launch_bounds__(256)
void prepack_w_kernel(const float* __restrict__ w, unsigned short* __restrict__ wp) {
    const int idx = blockIdx.x * 256 + threadIdx.x;      // 49152 = o*i*c*k
    const float v = w[idx];                              // coalesced
    const int k = idx % 3;
    int r = idx / 3;
    const int c = r & 3;  r >>= 2;
    const int i = r & 63;
    const int o = r >> 6;
    const int cc   = k * 2 + (i >> 5);
    const int lane = (((i >> 3) & 3) << 4) | (o & 15);
    const int j    = i & 7;
    const int wv   = o >> 4;
    wp[(((c * 4 + wv) * 6 + cc) * 64 + lane) * 8 + j] = f2bf(v);
}

// ---- staging: per chunk, thread (g2 = t>>3 in [0,32): 2-i group, q = t&7:
// l-quad) loads 2 f32x4 (2 i-rows, same l-quad) and writes 4 u32 LDS rows.
__device__ __forceinline__ void stage_load(const float* __restrict__ xb,
                                           int l0q, int g2, f32x4 s[2]) {
    const float* p = xb + (size_t)(2 * g2) * (NC * NL) + l0q;
    s[0] = *(const f32x4*)(p);
    s[1] = *(const f32x4*)(p + NC * NL);
}

__device__ __forceinline__ void stage_write(char* __restrict__ lds,
                                            int ch, int q, int g2,
                                            const f32x4 s[2]) {
#pragma unroll
    for (int r = 0; r < 4; ++r) {
        const int row = ch * LT + 4 * q + r + 1;         // rows 1..256
        const unsigned int pk =
            (unsigned int)f2bf(s[0][r]) | ((unsigned int)f2bf(s[1][r]) << 16);
        *(unsigned int*)(lds + row * ROWB + ((4 * g2) ^ ((row & 7) << 4))) = pk;
    }
}

// ---- compute one 32-l chunk: wave owns 16 o (o0 = wave*16), 2 l-subtiles
__device__ __forceinline__ void compute_chunk(const char* __restrict__ lds,
                                              const bf16x8 wfrag[6],
                                              const float* __restrict__ tb,
                                              float* __restrict__ ob,
                                              int ch, int lb0, int lane) {
    const int lcol  = lane & 15;
    const int ksub2 = (lane >> 4) * 16;
#pragma unroll
    for (int lt = 0; lt < 2; ++lt) {
        const int l0 = lb0 + ch * LT + lt * 16 + (lane >> 4) * 4;
        const f32x4 tv = *(const f32x4*)(tb + l0);
        f32x4 acc = {};
#pragma unroll
        for (int cc = 0; cc < 6; ++cc) {
            const int row = ch * LT + lt * 16 + lcol + (cc >> 1);
            const int off = row * ROWB + ((((cc & 1) << 6) + ksub2) ^ ((row & 7) << 4));
            const bf16x8 xf = *(const bf16x8*)(lds + off);
            acc = __builtin_amdgcn_mfma_f32_16x16x32_bf16(xf, wfrag[cc], acc, 0, 0, 0);
        }
        f32x4 r;
#pragma unroll
        for (int qq = 0; qq < 4; ++qq) r[qq] = acc[qq] * tv[qq];
        *(f32x4*)(ob + l0) = r;
    }
}

__global__ __launch_bounds__(256, 4)
void tconv_mfma_kernel(const float* __restrict__ x,
                       const float* __restrict__ tt,
                       const unsigned short* __restrict__ wp,
                       float* __restrict__ out)
{
    __shared__ char lds[LDSB];                           // 33 024 B

    const int t    = threadIdx.x;
    const int lane = t & 63;
    const int wave = t >> 6;
    const int c    = blockIdx.y;
    const int b    = blockIdx.z;
    const int lb0  = blockIdx.x * LBLK;
    const int g2   = t >> 3;                             // 0..31
    const int q    = t & 7;                              // 0..7
    const int lq   = 4 * q;

    const float* xb = x + ((size_t)b * NI * NC + c) * NL;
    const float* tb = tt + (size_t)(b * NC + c) * NL;
    float* ob = out + ((size_t)b * NO * NC
                       + (size_t)(wave * 16 + (lane & 15)) * NC + c) * NL;

    // ---- prologue: chunks 0,1 + halo loads first (HBM critical path)
    f32x4 sA[2], sB[2];
    stage_load(xb, lb0 + 0 * LT + lq, g2, sA);
    stage_load(xb, lb0 + 1 * LT + lq, g2, sB);
    float h = 0.f; int hrow = 0, hcol = 0;
    if (t < 128) {                                       // halo rows 0 and 257
        const int which = t & 1;
        const int i     = t >> 1;
        hrow = which ? (LBLK + 1) : 0;
        hcol = 2 * i;
        const int lh = which ? (lb0 + LBLK) : (lb0 - 1);
        if (lh >= 0 && lh < NL) h = xb[(size_t)i * (NC * NL) + lh];
    }

    // W fragments: 6 coalesced b128, L2-hot
    bf16x8 wfrag[6];
    {
        const bf16x8* wpb = (const bf16x8*)wp + (size_t)((c * 4 + wave) * 6) * 64 + lane;
#pragma unroll
        for (int cc = 0; cc < 6; ++cc) wfrag[cc] = wpb[cc * 64];
    }

    stage_write(lds, 0, q, g2, sA);
    stage_write(lds, 1, q, g2, sB);
    if (t < 128)
        *(unsigned short*)(lds + hrow * ROWB + (hcol ^ ((hrow & 7) << 4))) = f2bf(h);
    block_sync_lds();

    // ---- steady state: 6 of 8 iterations overlap load || compute+store || write
#pragma unroll
    for (int cn = 0; cn < NCH - 2; ++cn) {
        if ((cn & 1) == 0) {
            stage_load(xb, lb0 + (cn + 2) * LT + lq, g2, sA);
            compute_chunk(lds, wfrag, tb, ob, cn, lb0, lane);
            stage_write(lds, cn + 2, q, g2, sA);
        } else {
            stage_load(xb, lb0 + (cn + 2) * LT + lq, g2, sB);
            compute_chunk(lds, wfrag, tb, ob, cn, lb0, lane);
            stage_write(lds, cn + 2, q, g2, sB);
        }
        block_sync_lds();
    }

    // ---- drain
    compute_chunk(lds, wfrag, tb, ob, NCH - 2, lb0, lane);
    compute_chunk(lds, wfrag, tb, ob, NCH - 1, lb0, lane);
}

extern "C" void kernel_launch(void* const* d_in, const int* in_sizes, int n_in,
                              void* d_out, int out_size, void* d_ws, size_t ws_size,
                              hipStream_t stream) {
    const float* x  = (const float*)d_in[0];
    const float* tt = (const float*)d_in[1];
    const float* w  = (const float*)d_in[2];
    float* out = (float*)d_out;
    unsigned short* wpck = (unsigned short*)d_ws;

    prepack_w_kernel<<<dim3(NO * NI * NC * KW / 256), dim3(256), 0, stream>>>(w, wpck);

    dim3 grid(NL / LBLK, NC, NB);   // (16, 4, 16) = 1024 blocks
    tconv_mfma_kernel<<<grid, dim3(256), 0, stream>>>(x, tt, wpck, out);
}